// Round 1
// baseline (232.246 us; speedup 1.0000x reference)
//
#include <hip/hip_runtime.h>
#include <math.h>

#define R_ROUTES 1152
#define N_CAPS 10
#define C_IN 8
#define D_DIM 16
#define B_BATCH 128
#define JD 160                    // N_CAPS * D_DIM
#define RC (R_ROUTES * C_IN)      // 9216
#define RCHUNK 8
#define NCHUNK (R_ROUTES / RCHUNK) // 144

// ---------------------------------------------------------------------------
// ws layout (floats):
//   c_ij [1152][10]        @ 0          (11520)
//   b_ij [1152][10]        @ 11520      (11520)
//   xT   [9216][128]       @ 23040      (1179648)   xT[(r*8+c)*128 + b]
//   s    [160][128]        @ 1202688    (20480)     s[jd*128 + b]
//   v_ws [160][128]        @ 1223168    (20480)
//   part [144][160][128]   @ 1243648    (2949120)
// total 4,192,768 floats = 16.8 MB
// Every ws element is written before read each launch (re-poison safe).
// ---------------------------------------------------------------------------

// Transpose x[128][9216] -> xT[9216][128] via LDS 32x32 tiles.
__global__ void k_transpose(const float* __restrict__ x, float* __restrict__ xT) {
    __shared__ float tile[32][33];
    int bx = blockIdx.x;            // rc tile: 0..287
    int by = blockIdx.y;            // b tile: 0..3
    int tx = threadIdx.x & 31;
    int ty = threadIdx.x >> 5;      // 0..7
#pragma unroll
    for (int i = 0; i < 4; i++) {
        int row = ty + i * 8;       // b_local
        tile[row][tx] = x[(size_t)(by * 32 + row) * RC + bx * 32 + tx];
    }
    __syncthreads();
#pragma unroll
    for (int i = 0; i < 4; i++) {
        int row = ty + i * 8;       // rc_local
        xT[(size_t)(bx * 32 + row) * B_BATCH + by * 32 + tx] = tile[tx][row];
    }
}

// Split-K partial sums: part[chunk][jd][b] = sum_{r in chunk} c[r,j] * u_hat[b,r,jd]
// u_hat recomputed from W (scalar loads, wave-uniform jd) and x (registers).
template <bool UNIFORM_C>
__global__ __launch_bounds__(256) void k_s_partial(
    const float* __restrict__ xT, const float* __restrict__ W,
    const float* __restrict__ c_ij, float* __restrict__ part) {
    int chunk = blockIdx.x;              // 0..143
    int bh    = blockIdx.y;              // 0..1
    int jdq   = blockIdx.z;              // 0..1
    int lane  = threadIdx.x & 63;
    int wave  = threadIdx.x >> 6;        // 0..3
    int b  = bh * 64 + lane;
    int r0 = chunk * RCHUNK;

    // x fragment for this lane's b: 8 routes x 8 channels, coalesced loads
    float xv[RCHUNK][C_IN];
#pragma unroll
    for (int r = 0; r < RCHUNK; r++)
#pragma unroll
        for (int c = 0; c < C_IN; c++)
            xv[r][c] = xT[(size_t)((r0 + r) * C_IN + c) * B_BATCH + b];

    // force wave-uniform jd base -> W/c loads become scalar (s_load)
    int jd0 = __builtin_amdgcn_readfirstlane(jdq * 80 + wave * 20);

    for (int jj = 0; jj < 20; jj++) {
        int jd = jd0 + jj;
        int j  = jd >> 4;
        float acc = 0.f;
#pragma unroll
        for (int r = 0; r < RCHUNK; r++) {
            const float* wp = W + ((size_t)(r0 + r) * JD + jd) * C_IN;
            float uh = 0.f;
#pragma unroll
            for (int c = 0; c < C_IN; c++) uh = fmaf(wp[c], xv[r][c], uh);
            float cc = UNIFORM_C ? 0.1f : c_ij[(r0 + r) * N_CAPS + j];
            acc = fmaf(cc, uh, acc);
        }
        part[((size_t)chunk * JD + jd) * B_BATCH + b] = acc;  // coalesced
    }
}

// s[jd*128+b] = sum over 144 chunks (fully coalesced)
__global__ void k_reduce(const float* __restrict__ part, float* __restrict__ s) {
    int t = blockIdx.x * 256 + threadIdx.x;   // 0..20479
    float acc = 0.f;
#pragma unroll 8
    for (int ch = 0; ch < NCHUNK; ch++)
        acc += part[(size_t)ch * (JD * B_BATCH) + t];
    s[t] = acc;
}

// v = squash(s); writes internal layout v_ws[jd][b] and output out[b][j][d]
__global__ void k_squash(const float* __restrict__ s, float* __restrict__ v_ws,
                         float* __restrict__ out) {
    int t = blockIdx.x * 256 + threadIdx.x;   // 0..1279 -> (b, j)
    if (t >= B_BATCH * N_CAPS) return;
    int b = t & (B_BATCH - 1);
    int j = t >> 7;
    float sv[D_DIM];
    float sqn = 0.f;
#pragma unroll
    for (int d = 0; d < D_DIM; d++) {
        sv[d] = s[(j * D_DIM + d) * B_BATCH + b];
        sqn = fmaf(sv[d], sv[d], sqn);
    }
    float scale = sqn / ((1.f + sqn) * sqrtf(sqn));
#pragma unroll
    for (int d = 0; d < D_DIM; d++) {
        float vv = sv[d] * scale;
        v_ws[(j * D_DIM + d) * B_BATCH + b] = vv;
        out[(size_t)b * JD + j * D_DIM + d] = vv;
    }
}

// agreement + b_ij update + softmax -> c_ij, one block per route (owns b[r,:])
template <bool FIRST>
__global__ __launch_bounds__(128) void k_agree(
    const float* __restrict__ xT, const float* __restrict__ W,
    const float* __restrict__ v_ws, float* __restrict__ b_ij,
    float* __restrict__ c_ij) {
    int r = blockIdx.x;
    int b = threadIdx.x;            // 0..127
    int wave = b >> 6;

    float xv[C_IN];
#pragma unroll
    for (int c = 0; c < C_IN; c++)
        xv[c] = xT[(size_t)(r * C_IN + c) * B_BATCH + b];

    float accj[N_CAPS];
#pragma unroll
    for (int j = 0; j < N_CAPS; j++) {
        float acc = 0.f;
#pragma unroll
        for (int d = 0; d < D_DIM; d++) {
            const float* wp = W + ((size_t)r * JD + j * D_DIM + d) * C_IN;
            float uh = 0.f;
#pragma unroll
            for (int c = 0; c < C_IN; c++) uh = fmaf(wp[c], xv[c], uh);
            acc = fmaf(uh, v_ws[(j * D_DIM + d) * B_BATCH + b], acc);
        }
        accj[j] = acc;
    }
    // reduce over 64 lanes per wave
#pragma unroll
    for (int j = 0; j < N_CAPS; j++) {
        float a = accj[j];
#pragma unroll
        for (int off = 32; off > 0; off >>= 1)
            a += __shfl_down(a, off, 64);
        accj[j] = a;
    }
    __shared__ float red[2][N_CAPS];
    if ((b & 63) == 0) {
#pragma unroll
        for (int j = 0; j < N_CAPS; j++) red[wave][j] = accj[j];
    }
    __syncthreads();
    if (threadIdx.x == 0) {
        float bj[N_CAPS];
        float m = -1e30f;
#pragma unroll
        for (int j = 0; j < N_CAPS; j++) {
            float a = (red[0][j] + red[1][j]) * (1.f / B_BATCH);
            bj[j] = FIRST ? a : (b_ij[r * N_CAPS + j] + a);
            b_ij[r * N_CAPS + j] = bj[j];
            m = fmaxf(m, bj[j]);
        }
        float sum = 0.f, e[N_CAPS];
#pragma unroll
        for (int j = 0; j < N_CAPS; j++) { e[j] = expf(bj[j] - m); sum += e[j]; }
        float inv = 1.f / sum;
#pragma unroll
        for (int j = 0; j < N_CAPS; j++) c_ij[r * N_CAPS + j] = e[j] * inv;
    }
}

extern "C" void kernel_launch(void* const* d_in, const int* in_sizes, int n_in,
                              void* d_out, int out_size, void* d_ws, size_t ws_size,
                              hipStream_t stream) {
    const float* x = (const float*)d_in[0];   // [128,1152,8]
    const float* W = (const float*)d_in[1];   // [1,1152,10,16,8]
    float* out = (float*)d_out;               // [128,10,16,1]
    float* ws = (float*)d_ws;

    float* c_ij = ws;                          // 11520
    float* b_ij = ws + 11520;                  // 11520
    float* xT   = ws + 23040;                  // 1179648
    float* s    = ws + 23040 + 1179648;        // 20480
    float* v_ws = s + 20480;                   // 20480
    float* part = v_ws + 20480;                // 2949120

    k_transpose<<<dim3(288, 4), 256, 0, stream>>>(x, xT);

    // iter 0: c = softmax(0) = 0.1 uniform (no init kernel needed)
    k_s_partial<true><<<dim3(NCHUNK, 2, 2), 256, 0, stream>>>(xT, W, c_ij, part);
    k_reduce<<<80, 256, 0, stream>>>(part, s);
    k_squash<<<5, 256, 0, stream>>>(s, v_ws, out);
    k_agree<true><<<R_ROUTES, 128, 0, stream>>>(xT, W, v_ws, b_ij, c_ij);

    // iter 1
    k_s_partial<false><<<dim3(NCHUNK, 2, 2), 256, 0, stream>>>(xT, W, c_ij, part);
    k_reduce<<<80, 256, 0, stream>>>(part, s);
    k_squash<<<5, 256, 0, stream>>>(s, v_ws, out);
    k_agree<false><<<R_ROUTES, 128, 0, stream>>>(xT, W, v_ws, b_ij, c_ij);

    // iter 2 (final agreement skipped: it doesn't affect the returned v)
    k_s_partial<false><<<dim3(NCHUNK, 2, 2), 256, 0, stream>>>(xT, W, c_ij, part);
    k_reduce<<<80, 256, 0, stream>>>(part, s);
    k_squash<<<5, 256, 0, stream>>>(s, v_ws, out);
}

// Round 2
// 154.675 us; speedup vs baseline: 1.5015x; 1.5015x over previous
//
#include <hip/hip_runtime.h>
#include <math.h>

#define R_ROUTES 1152
#define N_CAPS 10
#define C_IN 8
#define D_DIM 16
#define B_BATCH 128
#define JD 160                      // N_CAPS * D_DIM
#define KK 9216                     // R_ROUTES * C_IN (GEMM K)
#define KSPLIT 32
#define KSTEPS_PER (288 / KSPLIT)   // 288 k-steps of 32, 9 per split

typedef __attribute__((ext_vector_type(8))) short short8;   // 8 bf16 (4 VGPRs)
typedef __attribute__((ext_vector_type(4))) float f32x4;    // MFMA accumulator

__device__ inline unsigned short f2bf(float f) {            // RNE fp32 -> bf16
    unsigned int u = __float_as_uint(f);
    unsigned int r = u + 0x7FFFu + ((u >> 16) & 1u);
    return (unsigned short)(r >> 16);
}
__device__ inline float bf2f(unsigned short h) {
    return __uint_as_float(((unsigned int)h) << 16);
}

// ---------------------------------------------------------------------------
// ws layout (byte offsets, all 256B-aligned):
//   b_ij   fp32 [1152][10]      @ 0          (46080 B)
//   x_hi   bf16 [128][9216]     @ 46080      (2359296 B)   A-operand layout [m][k]
//   x_lo   bf16 [128][9216]     @ 2405376
//   xT_hi  bf16 [9216][128]     @ 4764672    A-operand for M2 ([rc][b])
//   wc_hi  bf16 [160][9216]     @ 7123968    B-operand layout [n][k]
//   wc_lo  bf16 [160][9216]     @ 10073088
//   part   fp32 [32][128][160]  @ 13022208   split-K partials
//   v_bf16 bf16 [160][128]      @ 15643648   B-operand for M2 ([jd][b])
//   M2     fp32 [9216][160]     @ 15684608
// total ~21.6 MB. Everything written before read each launch (re-poison safe).
// ---------------------------------------------------------------------------

// prep: x -> x_hi/x_lo (same layout), xT_hi (transposed), zero b_ij
__global__ __launch_bounds__(256) void k_prep(
    const float* __restrict__ x, unsigned short* __restrict__ x_hi,
    unsigned short* __restrict__ x_lo, unsigned short* __restrict__ xT_hi,
    float* __restrict__ b_ij) {
    __shared__ float tile[32][33];
    int bx = blockIdx.x;            // rc tile 0..287
    int by = blockIdx.y;            // b tile 0..3
    int tx = threadIdx.x & 31;
    int ty = threadIdx.x >> 5;      // 0..7
#pragma unroll
    for (int i = 0; i < 4; i++) {
        int row = ty + i * 8;       // b_local
        size_t idx = (size_t)(by * 32 + row) * KK + bx * 32 + tx;
        float v = x[idx];
        tile[row][tx] = v;
        unsigned short hi = f2bf(v);
        x_hi[idx] = hi;
        x_lo[idx] = f2bf(v - bf2f(hi));
    }
    __syncthreads();
#pragma unroll
    for (int i = 0; i < 4; i++) {
        int row = ty + i * 8;       // rc_local
        xT_hi[(size_t)(bx * 32 + row) * B_BATCH + by * 32 + tx] = f2bf(tile[tx][row]);
    }
    if (by == 0) {
        int gid = bx * 256 + threadIdx.x;
        if (gid < R_ROUTES * N_CAPS) b_ij[gid] = 0.f;
    }
}

// build Wc^T (bf16 hi/lo, layout [jd][rc]) with c_ij folded; softmax(b_ij) inline
template <bool FIRST>
__global__ __launch_bounds__(256) void k_wc(
    const float* __restrict__ W, const float* __restrict__ b_ij,
    unsigned short* __restrict__ wc_hi, unsigned short* __restrict__ wc_lo) {
    __shared__ float cs[16][N_CAPS];
    __shared__ float wt[32][132];        // +4 pad: breaks 128-stride bank aliasing
    int rb = blockIdx.x;                 // 0..71 -> r0 = rb*16
    int jb = blockIdx.y;                 // 0..4  -> jd0 = jb*32
    int t  = threadIdx.x;
    int r0 = rb * 16, jd0 = jb * 32;

    if (!FIRST && t < 16) {
        int r = r0 + t;
        float bj[N_CAPS], m = -1e30f;
#pragma unroll
        for (int j = 0; j < N_CAPS; j++) { bj[j] = b_ij[r * N_CAPS + j]; m = fmaxf(m, bj[j]); }
        float sum = 0.f;
#pragma unroll
        for (int j = 0; j < N_CAPS; j++) { bj[j] = expf(bj[j] - m); sum += bj[j]; }
        float inv = 1.f / sum;
#pragma unroll
        for (int j = 0; j < N_CAPS; j++) cs[t][j] = bj[j] * inv;
    }
    __syncthreads();

    int jdl = t >> 3, c = t & 7;         // stage: 32 jd x 8 c per pass
#pragma unroll
    for (int rr = 0; rr < 16; rr++) {
        float w = W[((size_t)(r0 + rr) * JD + jd0 + jdl) * C_IN + c];
        float cc = FIRST ? 0.1f : cs[rr][(jd0 + jdl) >> 4];
        wt[jdl][rr * 8 + c] = w * cc;
    }
    __syncthreads();
#pragma unroll
    for (int p = 0; p < 16; p++) {
        int idx = p * 256 + t;
        int jl = idx >> 7, col = idx & 127;
        float v = wt[jl][col];
        unsigned short hi = f2bf(v);
        size_t o = (size_t)(jd0 + jl) * KK + rb * 128 + col;
        wc_hi[o] = hi;
        wc_lo[o] = f2bf(v - bf2f(hi));
    }
}

// s-GEMM: part[ks][b][jd] = x[b,:] . Wc^T[jd,:] over this split's K range.
// MFMA 16x16x32 bf16, frags straight from global, hi/lo 3-term split.
__global__ __launch_bounds__(256) void k_sgemm(
    const unsigned short* __restrict__ xh, const unsigned short* __restrict__ xl,
    const unsigned short* __restrict__ wh, const unsigned short* __restrict__ wl,
    float* __restrict__ part) {
    int ks = blockIdx.x;                 // 0..31
    int g  = blockIdx.y;                 // 0..19
    int w  = threadIdx.x >> 6;
    int l  = threadIdx.x & 63;
    int mn = g * 4 + w;                  // 0..79
    int mt = mn / 10, nt = mn % 10;
    int row = l & 15, quad = l >> 4;
    const short8* pa_h = (const short8*)(xh + (size_t)(mt * 16 + row) * KK);
    const short8* pa_l = (const short8*)(xl + (size_t)(mt * 16 + row) * KK);
    const short8* pb_h = (const short8*)(wh + (size_t)(nt * 16 + row) * KK);
    const short8* pb_l = (const short8*)(wl + (size_t)(nt * 16 + row) * KK);
    f32x4 acc = {0.f, 0.f, 0.f, 0.f};
#pragma unroll
    for (int s = 0; s < KSTEPS_PER; s++) {
        int k8 = (ks * KSTEPS_PER + s) * 4 + quad;   // short8 index
        short8 ah = pa_h[k8], al = pa_l[k8];
        short8 bh = pb_h[k8], bl = pb_l[k8];
        acc = __builtin_amdgcn_mfma_f32_16x16x32_bf16(ah, bh, acc, 0, 0, 0);
        acc = __builtin_amdgcn_mfma_f32_16x16x32_bf16(ah, bl, acc, 0, 0, 0);
        acc = __builtin_amdgcn_mfma_f32_16x16x32_bf16(al, bh, acc, 0, 0, 0);
    }
#pragma unroll
    for (int i = 0; i < 4; i++) {        // C/D: col=lane&15 (n), row=quad*4+i (m)
        int bo = mt * 16 + quad * 4 + i;
        part[((size_t)(ks * B_BATCH + bo)) * JD + nt * 16 + row] = acc[i];
    }
}

// reduce 32 split-K partials + squash; writes out (fp32) and v_bf16 [jd][b]
__global__ __launch_bounds__(320) void k_rs(
    const float* __restrict__ part, float* __restrict__ out,
    unsigned short* __restrict__ vb) {
    int t = threadIdx.x;                 // 320 = 2 b x 160 jd
    int bloc = t / JD, jd = t % JD;
    int b = blockIdx.x * 2 + bloc;
    float acc = 0.f;
#pragma unroll
    for (int ks = 0; ks < KSPLIT; ks++)
        acc += part[((size_t)(ks * B_BATCH + b)) * JD + jd];
    // jd%16 == lane%16 (160 and 64 are both multiples of 16), so width-16
    // xor-shuffles reduce over d within each (b,j) group.
    float sq = acc * acc;
#pragma unroll
    for (int off = 1; off < 16; off <<= 1) sq += __shfl_xor(sq, off, 16);
    float scale = sq / ((1.f + sq) * sqrtf(sq));
    float v = acc * scale;
    out[(size_t)b * JD + jd] = v;
    vb[(size_t)jd * B_BATCH + b] = f2bf(v);
}

// M2[rc][jd] = sum_b xT[rc][b] * v[jd][b]   (MFMA, single bf16 term)
__global__ __launch_bounds__(256) void k_m2(
    const unsigned short* __restrict__ xT, const unsigned short* __restrict__ vb,
    float* __restrict__ M2) {
    int w = threadIdx.x >> 6;
    int l = threadIdx.x & 63;
    int id = blockIdx.x * 4 + w;         // 0..5759
    int mt = id / 10, nt = id % 10;
    int row = l & 15, quad = l >> 4;
    const short8* pa = (const short8*)(xT + (size_t)(mt * 16 + row) * B_BATCH);
    const short8* pb = (const short8*)(vb + (size_t)(nt * 16 + row) * B_BATCH);
    f32x4 acc = {0.f, 0.f, 0.f, 0.f};
#pragma unroll
    for (int s = 0; s < 4; s++) {        // K = 128 = 4 steps of 32
        int k8 = s * 4 + quad;
        acc = __builtin_amdgcn_mfma_f32_16x16x32_bf16(pa[k8], pb[k8], acc, 0, 0, 0);
    }
#pragma unroll
    for (int i = 0; i < 4; i++) {
        int rco = mt * 16 + quad * 4 + i;
        M2[(size_t)rco * JD + nt * 16 + row] = acc[i];
    }
}

// b_ij[r][j] += (1/B) * sum_{c,d} W[r, j*16+d, c] * M2[(r,c), j*16+d]
__global__ __launch_bounds__(256) void k_bij(
    const float* __restrict__ W, const float* __restrict__ M2,
    float* __restrict__ b_ij) {
    int t = threadIdx.x;
    int rl = t >> 4, d = t & 15;
    int r = blockIdx.x * 16 + rl;
    float accj[N_CAPS];
#pragma unroll
    for (int j = 0; j < N_CAPS; j++) accj[j] = 0.f;
#pragma unroll
    for (int c = 0; c < C_IN; c++) {
#pragma unroll
        for (int j = 0; j < N_CAPS; j++) {
            float wv = W[((size_t)r * JD + j * D_DIM + d) * C_IN + c];
            float m2 = M2[((size_t)(r * C_IN + c)) * JD + j * D_DIM + d];
            accj[j] = fmaf(wv, m2, accj[j]);
        }
    }
#pragma unroll
    for (int j = 0; j < N_CAPS; j++) {
#pragma unroll
        for (int off = 1; off < 16; off <<= 1)
            accj[j] += __shfl_xor(accj[j], off, 16);
    }
    if (d == 0) {
#pragma unroll
        for (int j = 0; j < N_CAPS; j++)
            b_ij[r * N_CAPS + j] += accj[j] * (1.f / B_BATCH);
    }
}

extern "C" void kernel_launch(void* const* d_in, const int* in_sizes, int n_in,
                              void* d_out, int out_size, void* d_ws, size_t ws_size,
                              hipStream_t stream) {
    const float* x = (const float*)d_in[0];   // [128,1152,8]
    const float* W = (const float*)d_in[1];   // [1,1152,10,16,8]
    float* out = (float*)d_out;               // [128,10,16,1]
    char* ws = (char*)d_ws;

    float*          b_ij  = (float*)(ws + 0);
    unsigned short* x_hi  = (unsigned short*)(ws + 46080);
    unsigned short* x_lo  = (unsigned short*)(ws + 2405376);
    unsigned short* xT_hi = (unsigned short*)(ws + 4764672);
    unsigned short* wc_hi = (unsigned short*)(ws + 7123968);
    unsigned short* wc_lo = (unsigned short*)(ws + 10073088);
    float*          part  = (float*)(ws + 13022208);
    unsigned short* v_b   = (unsigned short*)(ws + 15643648);
    float*          M2    = (float*)(ws + 15684608);

    k_prep<<<dim3(288, 4), 256, 0, stream>>>(x, x_hi, x_lo, xT_hi, b_ij);

    // iter 1 (c uniform 0.1)
    k_wc<true><<<dim3(72, 5), 256, 0, stream>>>(W, b_ij, wc_hi, wc_lo);
    k_sgemm<<<dim3(KSPLIT, 20), 256, 0, stream>>>(x_hi, x_lo, wc_hi, wc_lo, part);
    k_rs<<<64, 320, 0, stream>>>(part, out, v_b);
    k_m2<<<1440, 256, 0, stream>>>(xT_hi, v_b, M2);
    k_bij<<<72, 256, 0, stream>>>(W, M2, b_ij);

    // iter 2
    k_wc<false><<<dim3(72, 5), 256, 0, stream>>>(W, b_ij, wc_hi, wc_lo);
    k_sgemm<<<dim3(KSPLIT, 20), 256, 0, stream>>>(x_hi, x_lo, wc_hi, wc_lo, part);
    k_rs<<<64, 320, 0, stream>>>(part, out, v_b);
    k_m2<<<1440, 256, 0, stream>>>(xT_hi, v_b, M2);
    k_bij<<<72, 256, 0, stream>>>(W, M2, b_ij);

    // iter 3 (final agreement not needed for output)
    k_wc<false><<<dim3(72, 5), 256, 0, stream>>>(W, b_ij, wc_hi, wc_lo);
    k_sgemm<<<dim3(KSPLIT, 20), 256, 0, stream>>>(x_hi, x_lo, wc_hi, wc_lo, part);
    k_rs<<<64, 320, 0, stream>>>(part, out, v_b);
}

// Round 3
// 145.855 us; speedup vs baseline: 1.5923x; 1.0605x over previous
//
#include <hip/hip_runtime.h>
#include <math.h>

#define R_ROUTES 1152
#define N_CAPS 10
#define C_IN 8
#define D_DIM 16
#define B_BATCH 128
#define JD 160                      // N_CAPS * D_DIM
#define KK 9216                     // R_ROUTES * C_IN (GEMM K)
#define KSPLIT 144                  // k-splits of 64 k (= 8 routes) each

typedef __attribute__((ext_vector_type(8))) short short8;   // 8 bf16 (4 VGPRs)
typedef __attribute__((ext_vector_type(4))) float f32x4;    // MFMA accumulator

__device__ inline unsigned short f2bf(float f) {            // RNE fp32 -> bf16
    unsigned int u = __float_as_uint(f);
    unsigned int r = u + 0x7FFFu + ((u >> 16) & 1u);
    return (unsigned short)(r >> 16);
}
__device__ inline float bf2f(unsigned short h) {
    return __uint_as_float(((unsigned int)h) << 16);
}

// ---------------------------------------------------------------------------
// ws layout (byte offsets):
//   b_ij  fp32 [1152][10]       @ 0
//   x_hi  bf16 [128][9216]      @ 46080       A-operand layout [m][k]
//   x_lo  bf16 [128][9216]      @ 2405376
//   xT_hi bf16 [9216][128]      @ 4764672     A-operand for agree ([rc][b])
//   part  fp32 [144][128][160]  @ 7123968     split-K partials (11.8 MB)
//   v_b   bf16 [160][128]       @ 18920448    B-operand for agree ([jd][b])
// total ~19 MB. Everything written before read each launch (re-poison safe).
// ---------------------------------------------------------------------------

// prep: x -> x_hi/x_lo (same layout), xT_hi (transposed), zero b_ij
__global__ __launch_bounds__(256) void k_prep(
    const float* __restrict__ x, unsigned short* __restrict__ x_hi,
    unsigned short* __restrict__ x_lo, unsigned short* __restrict__ xT_hi,
    float* __restrict__ b_ij) {
    __shared__ float tile[32][33];
    int bx = blockIdx.x;            // rc tile 0..287
    int by = blockIdx.y;            // b tile 0..3
    int tx = threadIdx.x & 31;
    int ty = threadIdx.x >> 5;      // 0..7
#pragma unroll
    for (int i = 0; i < 4; i++) {
        int row = ty + i * 8;       // b_local
        size_t idx = (size_t)(by * 32 + row) * KK + bx * 32 + tx;
        float v = x[idx];
        tile[row][tx] = v;
        unsigned short hi = f2bf(v);
        x_hi[idx] = hi;
        x_lo[idx] = f2bf(v - bf2f(hi));
    }
    __syncthreads();
#pragma unroll
    for (int i = 0; i < 4; i++) {
        int row = ty + i * 8;       // rc_local
        xT_hi[(size_t)(bx * 32 + row) * B_BATCH + by * 32 + tx] = f2bf(tile[tx][row]);
    }
    if (by == 0) {
        int gid = bx * 256 + threadIdx.x;
        if (gid < R_ROUTES * N_CAPS) b_ij[gid] = 0.f;
    }
}

// Fused per-iteration GEMM: softmax(b_ij) -> c, build c*W bf16 hi/lo slice in
// LDS (W read once chip-wide), then MFMA: part[ks][b][jd] over this block's
// 64-k range and 32-jd range. Grid (144, 5), block 256.
template <bool FIRST>
__global__ __launch_bounds__(256) void k_iter(
    const unsigned short* __restrict__ xh, const unsigned short* __restrict__ xl,
    const float* __restrict__ W, const float* __restrict__ b_ij,
    float* __restrict__ part) {
    __shared__ float cs[8][N_CAPS];
    __shared__ unsigned short bhs[32][72];   // [jd_local][k_local], +8 pad
    __shared__ unsigned short bls[32][72];
    int t  = threadIdx.x;
    int ks = blockIdx.x;                 // k range: ks*64 .. +64 (routes ks*8..+8)
    int ng = blockIdx.y;                 // jd range: ng*32 .. +32
    int r0 = ks * 8, jd0 = ng * 32;

    if (!FIRST && t < 8) {               // softmax over caps for this block's routes
        float bj[N_CAPS], m = -1e30f;
#pragma unroll
        for (int j = 0; j < N_CAPS; j++) { bj[j] = b_ij[(r0 + t) * N_CAPS + j]; m = fmaxf(m, bj[j]); }
        float sum = 0.f;
#pragma unroll
        for (int j = 0; j < N_CAPS; j++) { bj[j] = expf(bj[j] - m); sum += bj[j]; }
        float inv = 1.f / sum;
#pragma unroll
        for (int j = 0; j < N_CAPS; j++) cs[t][j] = bj[j] * inv;
    }
    __syncthreads();

    {   // stage c*W slice: 8 routes x 32 jd = 256 (r,jd) pairs, one per thread
        int jdl = t & 31, rl = t >> 5;
        const float* wp = W + ((size_t)(r0 + rl) * JD + jd0 + jdl) * C_IN;
        float c = FIRST ? 0.1f : cs[rl][(jd0 + jdl) >> 4];
        short8 vh, vl;
#pragma unroll
        for (int i = 0; i < 8; i++) {
            float cw = wp[i] * c;
            unsigned short hi = f2bf(cw);
            vh[i] = (short)hi;
            vl[i] = (short)f2bf(cw - bf2f(hi));
        }
        *(short8*)&bhs[jdl][rl * 8] = vh;    // k_local = rl*8 + c  (16B aligned)
        *(short8*)&bls[jdl][rl * 8] = vl;
    }
    __syncthreads();

    int w = t >> 6, l = t & 63;
    int row = l & 15, quad = l >> 4;
    // B frags for both n-tiles and both k-steps (reused across m-tiles)
    short8 Bh[2][2], Bl[2][2];
#pragma unroll
    for (int nt = 0; nt < 2; nt++)
#pragma unroll
        for (int st = 0; st < 2; st++) {
            Bh[nt][st] = *(const short8*)&bhs[nt * 16 + row][st * 32 + quad * 8];
            Bl[nt][st] = *(const short8*)&bls[nt * 16 + row][st * 32 + quad * 8];
        }
#pragma unroll
    for (int mi = 0; mi < 2; mi++) {
        int mt = w + mi * 4;             // m-tile 0..7 (batch rows mt*16..+16)
        const short8* pah = (const short8*)(xh + (size_t)(mt * 16 + row) * KK + ks * 64);
        const short8* pal = (const short8*)(xl + (size_t)(mt * 16 + row) * KK + ks * 64);
        short8 ah0 = pah[quad], ah1 = pah[4 + quad];
        short8 al0 = pal[quad], al1 = pal[4 + quad];
#pragma unroll
        for (int nt = 0; nt < 2; nt++) {
            f32x4 acc = {0.f, 0.f, 0.f, 0.f};
            acc = __builtin_amdgcn_mfma_f32_16x16x32_bf16(ah0, Bh[nt][0], acc, 0, 0, 0);
            acc = __builtin_amdgcn_mfma_f32_16x16x32_bf16(ah0, Bl[nt][0], acc, 0, 0, 0);
            acc = __builtin_amdgcn_mfma_f32_16x16x32_bf16(al0, Bh[nt][0], acc, 0, 0, 0);
            acc = __builtin_amdgcn_mfma_f32_16x16x32_bf16(ah1, Bh[nt][1], acc, 0, 0, 0);
            acc = __builtin_amdgcn_mfma_f32_16x16x32_bf16(ah1, Bl[nt][1], acc, 0, 0, 0);
            acc = __builtin_amdgcn_mfma_f32_16x16x32_bf16(al1, Bh[nt][1], acc, 0, 0, 0);
#pragma unroll
            for (int i = 0; i < 4; i++) {    // C/D: col=lane&15 (jd), row=quad*4+i (b)
                int b = mt * 16 + quad * 4 + i;
                part[((size_t)(ks * B_BATCH + b)) * JD + jd0 + nt * 16 + row] = acc[i];
            }
        }
    }
}

// reduce 144 split-K partials + squash; writes out (fp32) and v_b [jd][b]
__global__ __launch_bounds__(320) void k_rs(
    const float* __restrict__ part, float* __restrict__ out,
    unsigned short* __restrict__ vb) {
    int t = threadIdx.x;                 // 320 = 2 b x 160 jd
    int bloc = t / JD, jd = t % JD;
    int b = blockIdx.x * 2 + bloc;
    float acc = 0.f;
#pragma unroll 4
    for (int ks = 0; ks < KSPLIT; ks++)
        acc += part[((size_t)(ks * B_BATCH + b)) * JD + jd];
    float sq = acc * acc;                // reduce over d: lane%16 == jd%16
#pragma unroll
    for (int off = 1; off < 16; off <<= 1) sq += __shfl_xor(sq, off, 16);
    float scale = sq / ((1.f + sq) * sqrtf(sq));
    float v = acc * scale;
    out[(size_t)b * JD + jd] = v;
    vb[(size_t)jd * B_BATCH + b] = f2bf(v);
}

// Fused agreement: M2 tile (16 rc x 160 jd) via MFMA into LDS, then
// b_ij[r][j] += (1/B) sum_{c,d} W[r,jd,c] * M2[(r,c),jd].  Block owns 2 routes.
__global__ __launch_bounds__(320) void k_agree(
    const unsigned short* __restrict__ xT, const unsigned short* __restrict__ vb,
    const float* __restrict__ W, float* __restrict__ b_ij) {
    __shared__ float m2[16][164];        // [rc_local][jd], +4 pad
    int t = threadIdx.x;                 // 320 = 5 waves
    int w = t >> 6, l = t & 63;
    int row = l & 15, quad = l >> 4;
    int rc0 = blockIdx.x * 16;           // routes blockIdx.x*2, +1
#pragma unroll
    for (int ni = 0; ni < 2; ni++) {
        int nt = w * 2 + ni;             // n-tile 0..9
        const short8* pa = (const short8*)(xT + (size_t)(rc0 + row) * B_BATCH);
        const short8* pb = (const short8*)(vb + (size_t)(nt * 16 + row) * B_BATCH);
        f32x4 acc = {0.f, 0.f, 0.f, 0.f};
#pragma unroll
        for (int s = 0; s < 4; s++)      // K = 128 = 4 steps of 32
            acc = __builtin_amdgcn_mfma_f32_16x16x32_bf16(pa[s * 4 + quad], pb[s * 4 + quad], acc, 0, 0, 0);
#pragma unroll
        for (int i = 0; i < 4; i++)      // C/D: col=jd offset, row=rc offset
            m2[quad * 4 + i][nt * 16 + row] = acc[i];
    }
    __syncthreads();
    int rl = t / 160, j = (t % 160) / 16, d = t % 16;
    const float* wp = W + ((size_t)(blockIdx.x * 2 + rl) * JD + j * D_DIM + d) * C_IN;
    float a = 0.f;
#pragma unroll
    for (int c = 0; c < 8; c++)
        a = fmaf(wp[c], m2[rl * 8 + c][j * D_DIM + d], a);
#pragma unroll
    for (int off = 1; off < 16; off <<= 1) a += __shfl_xor(a, off, 16);
    if (d == 0)
        b_ij[(blockIdx.x * 2 + rl) * N_CAPS + j] += a * (1.f / B_BATCH);
}

extern "C" void kernel_launch(void* const* d_in, const int* in_sizes, int n_in,
                              void* d_out, int out_size, void* d_ws, size_t ws_size,
                              hipStream_t stream) {
    const float* x = (const float*)d_in[0];   // [128,1152,8]
    const float* W = (const float*)d_in[1];   // [1,1152,10,16,8]
    float* out = (float*)d_out;               // [128,10,16,1]
    char* ws = (char*)d_ws;

    float*          b_ij  = (float*)(ws + 0);
    unsigned short* x_hi  = (unsigned short*)(ws + 46080);
    unsigned short* x_lo  = (unsigned short*)(ws + 2405376);
    unsigned short* xT_hi = (unsigned short*)(ws + 4764672);
    float*          part  = (float*)(ws + 7123968);
    unsigned short* v_b   = (unsigned short*)(ws + 18920448);

    k_prep<<<dim3(288, 4), 256, 0, stream>>>(x, x_hi, x_lo, xT_hi, b_ij);

    // iter 1 (c uniform 0.1)
    k_iter<true><<<dim3(KSPLIT, 5), 256, 0, stream>>>(x_hi, x_lo, W, b_ij, part);
    k_rs<<<64, 320, 0, stream>>>(part, out, v_b);
    k_agree<<<576, 320, 0, stream>>>(xT_hi, v_b, W, b_ij);

    // iter 2
    k_iter<false><<<dim3(KSPLIT, 5), 256, 0, stream>>>(x_hi, x_lo, W, b_ij, part);
    k_rs<<<64, 320, 0, stream>>>(part, out, v_b);
    k_agree<<<576, 320, 0, stream>>>(xT_hi, v_b, W, b_ij);

    // iter 3 (final agreement not needed for output)
    k_iter<false><<<dim3(KSPLIT, 5), 256, 0, stream>>>(x_hi, x_lo, W, b_ij, part);
    k_rs<<<64, 320, 0, stream>>>(part, out, v_b);
}